// Round 6
// baseline (7919.424 us; speedup 1.0000x reference)
//
#include <hip/hip_runtime.h>
#include <cstdint>
#include <cstddef>

#define H      128
#define IN_    12
#define GATES  512   // 4*H
#define B_     256
#define T_     2048
#define TCMAX  512
#define TT     64    // gemm time-tile

#define REP32(M) M(0) M(1) M(2) M(3) M(4) M(5) M(6) M(7) M(8) M(9) M(10) M(11) \
  M(12) M(13) M(14) M(15) M(16) M(17) M(18) M(19) M(20) M(21) M(22) M(23) \
  M(24) M(25) M(26) M(27) M(28) M(29) M(30) M(31)

__device__ __forceinline__ float sigmoidf_(float x) {
    return 1.f / (1.f + __expf(-x));
}
__device__ __forceinline__ float tanhf_(float x) {
    return 2.f / (1.f + __expf(-2.f * x)) - 1.f;
}
__device__ __forceinline__ float dot4f(float4 w, float4 h, float a) {
    return fmaf(w.x, h.x, fmaf(w.y, h.y, fmaf(w.z, h.z, fmaf(w.w, h.w, a))));
}

// ======================= LSTM scan (both layers) =======================
// 1024 threads = 16 waves. thread -> (ks = tid>>7 wave-uniform k-window,
// q = tid&127 hidden index). Thread owns the 4 GATE rows of hidden q
// (rows q, 128+q, 256+q, 384+q), k-window [16ks,16ks+16) -> 16 float4 = 64 VGPR.
// Gate-major row ownership => phase-1 partial = one ds_write_b128 at
// [ks][q], phase-2 = 8 conflict-free ds_read_b128 at [ks][tid]
// (round-4 layout had 32 b32 reads at 4-way conflict: 2.5e7/dispatch).
template<bool IS_L0>
__global__ __launch_bounds__(1024) void lstm_scan(
    const float* __restrict__ x_or_gx,   // L0: x [B,T,12]; L1: gx chunk [B,tc,512]
    const float* __restrict__ Wih,       // L0 only [512,12]
    const float* __restrict__ Whh,       // [512,128]
    const float* __restrict__ bih, const float* __restrict__ bhh, // L0 only
    float* __restrict__ hs0,             // L0: out [B,tc,128]; L1: unused
    float* __restrict__ state,           // [B,2,128]
    int tc, int chunk)
{
    const int b   = blockIdx.x;
    const int tid = threadIdx.x;
    const int ks  = tid >> 7;    // 0..7, wave-uniform
    const int q   = tid & 127;   // hidden index

    extern __shared__ float smem[];
    float* sh_part = smem;                  // [8][128] float4 = 16 KB
    float* sh_h    = smem + 8 * 512;        // 128
    float* sh_x    = sh_h + H;              // L0: tc*12

    // resident W_hh fragment: gate rows i*128+q, cols 16ks..16ks+15
#define LOADW(i) \
    const float4* wr##i = (const float4*)(Whh + (size_t)(i * H + q) * H + 16 * ks); \
    float4 w##i##0 = wr##i[0], w##i##1 = wr##i[1], w##i##2 = wr##i[2], w##i##3 = wr##i[3];
    LOADW(0) LOADW(1) LOADW(2) LOADW(3)
#undef LOADW

    // L0: x-proj weights for ks 1..3 (4 floats per gate row)
    float4 wx0 = {0,0,0,0}, wx1 = {0,0,0,0}, wx2 = {0,0,0,0}, wx3 = {0,0,0,0};
    if constexpr (IS_L0) {
        if (ks >= 1 && ks <= 3) {
            wx0 = *(const float4*)(Wih + (size_t)(0 * H + q) * IN_ + 4 * (ks - 1));
            wx1 = *(const float4*)(Wih + (size_t)(1 * H + q) * IN_ + 4 * (ks - 1));
            wx2 = *(const float4*)(Wih + (size_t)(2 * H + q) * IN_ + 4 * (ks - 1));
            wx3 = *(const float4*)(Wih + (size_t)(3 * H + q) * IN_ + 4 * (ks - 1));
        }
        const float* xs = x_or_gx + ((size_t)b * T_ + (size_t)chunk * tc) * IN_;
        for (int i = tid; i < tc * IN_; i += 1024) sh_x[i] = xs[i];
    }

    // epilogue-thread state (tid<128)
    float bias0 = 0, bias1 = 0, bias2 = 0, bias3 = 0;
    float cur0 = 0, cur1 = 0, cur2 = 0, cur3 = 0;
    float hreg = 0.f, creg = 0.f;
    const float* gxb = nullptr;
    if constexpr (!IS_L0) gxb = x_or_gx + (size_t)b * tc * GATES;

    if (tid < H) {
        if constexpr (IS_L0) {
            bias0 = bih[tid]       + bhh[tid];
            bias1 = bih[tid + 128] + bhh[tid + 128];
            bias2 = bih[tid + 256] + bhh[tid + 256];
            bias3 = bih[tid + 384] + bhh[tid + 384];
        } else {
            cur0 = gxb[tid]; cur1 = gxb[tid + 128];
            cur2 = gxb[tid + 256]; cur3 = gxb[tid + 384];
        }
        if (chunk) { hreg = state[b*2*H + tid]; creg = state[b*2*H + H + tid]; }
        sh_h[tid] = hreg;
    }
    __syncthreads();

    float* hs_out = nullptr;
    if constexpr (IS_L0) hs_out = hs0 + (size_t)b * tc * H;

    const float4* sh4 = (const float4*)sh_h;
    float4* sp4w = (float4*)sh_part;
    const float4* sp4 = (const float4*)sh_part;

    for (int t = 0; t < tc; ++t) {
        // ---- phase 1: partial dots (all 16 waves) ----
        float n0 = 0, n1 = 0, n2 = 0, n3 = 0;   // next-step gx prefetch (L1)
        if constexpr (!IS_L0) {
            if (tid < H) {
                int tn = (t + 1 < tc) ? t + 1 : t;
                const float* gp = gxb + (size_t)tn * GATES;
                n0 = gp[tid]; n1 = gp[tid + 128];
                n2 = gp[tid + 256]; n3 = gp[tid + 384];
            }
        }
        float4 hA = sh4[4*ks], hB = sh4[4*ks+1], hC = sh4[4*ks+2], hD = sh4[4*ks+3];
        float a0 = dot4f(w03,hD, dot4f(w02,hC, dot4f(w01,hB, dot4f(w00,hA, 0.f))));
        float a1 = dot4f(w13,hD, dot4f(w12,hC, dot4f(w11,hB, dot4f(w10,hA, 0.f))));
        float a2 = dot4f(w23,hD, dot4f(w22,hC, dot4f(w21,hB, dot4f(w20,hA, 0.f))));
        float a3 = dot4f(w33,hD, dot4f(w32,hC, dot4f(w31,hB, dot4f(w30,hA, 0.f))));
        if constexpr (IS_L0) {
            if (ks >= 1 && ks <= 3) {
                float4 xq = *(const float4*)(sh_x + t * IN_ + 4 * (ks - 1));
                a0 = dot4f(wx0, xq, a0); a1 = dot4f(wx1, xq, a1);
                a2 = dot4f(wx2, xq, a2); a3 = dot4f(wx3, xq, a3);
            }
        }
        float4 av; av.x = a0; av.y = a1; av.z = a2; av.w = a3;
        sp4w[ks * 128 + q] = av;                 // one ds_write_b128
        __syncthreads();

        // ---- phase 2: reduce + activate + state update (tid<128) ----
        if (tid < H) {
            float pi = 0, pf = 0, pg = 0, po = 0;
#define RQ(m) { float4 v = sp4[m * 128 + tid]; pi += v.x; pf += v.y; pg += v.z; po += v.w; }
            RQ(0) RQ(1) RQ(2) RQ(3) RQ(4) RQ(5) RQ(6) RQ(7)
#undef RQ
            float gi, gf, gg, go;
            if constexpr (IS_L0) {
                gi = pi + bias0; gf = pf + bias1; gg = pg + bias2; go = po + bias3;
            } else {
                gi = pi + cur0; gf = pf + cur1; gg = pg + cur2; go = po + cur3;
                cur0 = n0; cur1 = n1; cur2 = n2; cur3 = n3;
            }
            creg = fmaf(sigmoidf_(gf), creg, sigmoidf_(gi) * tanhf_(gg));
            hreg = sigmoidf_(go) * tanhf_(creg);
            sh_h[tid] = hreg;
            if constexpr (IS_L0) hs_out[(size_t)t * H + tid] = hreg;
        }
        __syncthreads();
    }
    if (tid < H) { state[b*2*H + tid] = hreg; state[b*2*H + H + tid] = creg; }
}

// ======================= gx1 GEMM =======================
// gx1[b,t,g] = bias1[g] + sum_k hs0[b,t,k] * Wih1[g,k]
// 512 threads, thread = gate g; block = (b, 64-step tile).
// W row pinned in 32 NAMED float4 BEFORE the t-loop (round 4: compiler
// interchanged the loops and re-streamed W per t -> 30ms dispatch, VGPR=28).
// h-tile read through block-uniform pointers -> scalar s_load; each FMA is
// v_fma(v_w, s_h, acc): no LDS, no per-lane vector loads except gx store.
__global__ __launch_bounds__(512)
__attribute__((amdgpu_waves_per_eu(2, 2)))
void gx1_gemm(const float* __restrict__ hs0, const float* __restrict__ Wih,
              const float* __restrict__ bih, const float* __restrict__ bhh,
              float* __restrict__ gx, int tc)
{
    const int b  = blockIdx.x;
    const int t0 = blockIdx.y * TT;
    const int g  = threadIdx.x;

#define LWG(j) float4 w##j = ((const float4*)(Wih + (size_t)g * H))[j];
    REP32(LWG)
#undef LWG
    const float biasg = bih[g] + bhh[g];

    const float* hp = hs0 + ((size_t)b * tc + t0) * H;      // block-uniform
    float* gxo = gx + ((size_t)b * tc + t0) * GATES + g;

    for (int t = 0; t < TT; ++t) {
        const float4* h4 = (const float4*)(hp + (size_t)t * H);  // uniform -> s_load
        float a0 = biasg, a1 = 0.f, a2 = 0.f, a3 = 0.f;
#define G4(i0,i1,i2,i3) \
        a0 = dot4f(w##i0, h4[i0], a0); a1 = dot4f(w##i1, h4[i1], a1); \
        a2 = dot4f(w##i2, h4[i2], a2); a3 = dot4f(w##i3, h4[i3], a3);
        G4(0,1,2,3)    G4(4,5,6,7)    G4(8,9,10,11)   G4(12,13,14,15)
        G4(16,17,18,19) G4(20,21,22,23) G4(24,25,26,27) G4(28,29,30,31)
#undef G4
        gxo[(size_t)t * GATES] = (a0 + a1) + (a2 + a3);     // coalesced b32
    }
}

// ======================= output projection =======================
__global__ void out_proj(const float* __restrict__ state1,
                         const float* __restrict__ Wout,
                         const float* __restrict__ bout,
                         float* __restrict__ out)
{
    const int b = blockIdx.x, j = threadIdx.x;
    __shared__ float sh[H];
    if (j < H) sh[j] = state1[b*2*H + j];
    __syncthreads();
    if (j < 4) {
        float a = bout[j];
        for (int k = 0; k < H; ++k) a = fmaf(Wout[j*H + k], sh[k], a);
        out[b*4 + j] = a;
    }
}

extern "C" void kernel_launch(void* const* d_in, const int* in_sizes, int n_in,
                              void* d_out, int out_size, void* d_ws, size_t ws_size,
                              hipStream_t stream)
{
    const float* x    = (const float*)d_in[0];
    const float* Wih0 = (const float*)d_in[1];
    const float* Whh0 = (const float*)d_in[2];
    const float* bih0 = (const float*)d_in[3];
    const float* bhh0 = (const float*)d_in[4];
    const float* Wih1 = (const float*)d_in[5];
    const float* Whh1 = (const float*)d_in[6];
    const float* bih1 = (const float*)d_in[7];
    const float* bhh1 = (const float*)d_in[8];
    const float* Wout = (const float*)d_in[9];
    const float* bout = (const float*)d_in[10];

    // ws layout: st0 | st1 | hs0 chunk | gx1 chunk  (tc >= TT for gemm grid)
    int tc = TT;
    for (int cand = TCMAX; cand >= TT; cand >>= 1) {
        size_t need = (size_t)2 * B_ * 2 * H * 4
                    + (size_t)B_ * cand * H * 4
                    + (size_t)B_ * cand * GATES * 4;
        if (need <= ws_size) { tc = cand; break; }
    }

    float* ws  = (float*)d_ws;
    float* st0 = ws;
    float* st1 = st0 + (size_t)B_ * 2 * H;
    float* hs0 = st1 + (size_t)B_ * 2 * H;
    float* gx1 = hs0 + (size_t)B_ * tc * H;

    const size_t shm_l0 = (size_t)(8 * 512 + H + tc * IN_) * 4;
    const size_t shm_l1 = (size_t)(8 * 512 + H) * 4;

    const int nchunks = T_ / tc;
    for (int c = 0; c < nchunks; ++c) {
        lstm_scan<true><<<B_, 1024, shm_l0, stream>>>(
            x, Wih0, Whh0, bih0, bhh0, hs0, st0, tc, c);
        gx1_gemm<<<dim3(B_, tc / TT), 512, 0, stream>>>(
            hs0, Wih1, bih1, bhh1, gx1, tc);
        lstm_scan<false><<<B_, 1024, shm_l1, stream>>>(
            gx1, nullptr, Whh1, nullptr, nullptr, nullptr, st1, tc, c);
    }
    out_proj<<<B_, 128, 0, stream>>>(st1, Wout, bout, (float*)d_out);
}

// Round 7
// 7910.406 us; speedup vs baseline: 1.0011x; 1.0011x over previous
//
#include <hip/hip_runtime.h>
#include <cstdint>
#include <cstddef>

#define H      128
#define IN_    12
#define GATES  512   // 4*H
#define B_     256
#define T_     2048
#define TCMAX  512
#define TT     64    // gemm time-tile

#define REP32(M) M(0) M(1) M(2) M(3) M(4) M(5) M(6) M(7) M(8) M(9) M(10) M(11) \
  M(12) M(13) M(14) M(15) M(16) M(17) M(18) M(19) M(20) M(21) M(22) M(23) \
  M(24) M(25) M(26) M(27) M(28) M(29) M(30) M(31)

__device__ __forceinline__ float sigmoidf_(float x) {
    return 1.f / (1.f + __expf(-x));
}
__device__ __forceinline__ float tanhf_(float x) {
    return 2.f / (1.f + __expf(-2.f * x)) - 1.f;
}
__device__ __forceinline__ float dot4f(float4 w, float4 h, float a) {
    return fmaf(w.x, h.x, fmaf(w.y, h.y, fmaf(w.z, h.z, fmaf(w.w, h.w, a))));
}

// ======================= LSTM scan (both layers) =======================
// 1024 threads = 16 waves. thread -> (ks = tid>>7 wave-uniform k-window,
// q = tid&127 hidden index). Thread owns the 4 GATE rows of hidden q
// (rows q, 128+q, 256+q, 384+q), k-window [16ks,16ks+16) -> 16 float4 = 64 VGPR.
// Gate-major row ownership => phase-1 partial = one ds_write_b128 at
// [ks][q], phase-2 = 8 conflict-free ds_read_b128 at [ks][tid]
// (round-4 layout had 32 b32 reads at 4-way conflict: 2.5e7/dispatch).
template<bool IS_L0>
__global__ __launch_bounds__(1024) void lstm_scan(
    const float* __restrict__ x_or_gx,   // L0: x [B,T,12]; L1: gx chunk [B,tc,512]
    const float* __restrict__ Wih,       // L0 only [512,12]
    const float* __restrict__ Whh,       // [512,128]
    const float* __restrict__ bih, const float* __restrict__ bhh, // L0 only
    float* __restrict__ hs0,             // L0: out [B,tc,128]; L1: unused
    float* __restrict__ state,           // [B,2,128]
    int tc, int chunk)
{
    const int b   = blockIdx.x;
    const int tid = threadIdx.x;
    const int ks  = tid >> 7;    // 0..7, wave-uniform
    const int q   = tid & 127;   // hidden index

    extern __shared__ float smem[];
    float* sh_part = smem;                  // [8][128] float4 = 16 KB
    float* sh_h    = smem + 8 * 512;        // 128
    float* sh_x    = sh_h + H;              // L0: tc*12

    // resident W_hh fragment: gate rows i*128+q, cols 16ks..16ks+15
#define LOADW(i) \
    const float4* wr##i = (const float4*)(Whh + (size_t)(i * H + q) * H + 16 * ks); \
    float4 w##i##0 = wr##i[0], w##i##1 = wr##i[1], w##i##2 = wr##i[2], w##i##3 = wr##i[3];
    LOADW(0) LOADW(1) LOADW(2) LOADW(3)
#undef LOADW

    // L0: x-proj weights for ks 1..3 (4 floats per gate row)
    float4 wx0 = {0,0,0,0}, wx1 = {0,0,0,0}, wx2 = {0,0,0,0}, wx3 = {0,0,0,0};
    if constexpr (IS_L0) {
        if (ks >= 1 && ks <= 3) {
            wx0 = *(const float4*)(Wih + (size_t)(0 * H + q) * IN_ + 4 * (ks - 1));
            wx1 = *(const float4*)(Wih + (size_t)(1 * H + q) * IN_ + 4 * (ks - 1));
            wx2 = *(const float4*)(Wih + (size_t)(2 * H + q) * IN_ + 4 * (ks - 1));
            wx3 = *(const float4*)(Wih + (size_t)(3 * H + q) * IN_ + 4 * (ks - 1));
        }
        const float* xs = x_or_gx + ((size_t)b * T_ + (size_t)chunk * tc) * IN_;
        for (int i = tid; i < tc * IN_; i += 1024) sh_x[i] = xs[i];
    }

    // epilogue-thread state (tid<128)
    float bias0 = 0, bias1 = 0, bias2 = 0, bias3 = 0;
    float cur0 = 0, cur1 = 0, cur2 = 0, cur3 = 0;
    float hreg = 0.f, creg = 0.f;
    const float* gxb = nullptr;
    if constexpr (!IS_L0) gxb = x_or_gx + (size_t)b * tc * GATES;

    if (tid < H) {
        if constexpr (IS_L0) {
            bias0 = bih[tid]       + bhh[tid];
            bias1 = bih[tid + 128] + bhh[tid + 128];
            bias2 = bih[tid + 256] + bhh[tid + 256];
            bias3 = bih[tid + 384] + bhh[tid + 384];
        } else {
            cur0 = gxb[tid]; cur1 = gxb[tid + 128];
            cur2 = gxb[tid + 256]; cur3 = gxb[tid + 384];
        }
        if (chunk) { hreg = state[b*2*H + tid]; creg = state[b*2*H + H + tid]; }
        sh_h[tid] = hreg;
    }
    __syncthreads();

    float* hs_out = nullptr;
    if constexpr (IS_L0) hs_out = hs0 + (size_t)b * tc * H;

    const float4* sh4 = (const float4*)sh_h;
    float4* sp4w = (float4*)sh_part;
    const float4* sp4 = (const float4*)sh_part;

    for (int t = 0; t < tc; ++t) {
        // ---- phase 1: partial dots (all 16 waves) ----
        float n0 = 0, n1 = 0, n2 = 0, n3 = 0;   // next-step gx prefetch (L1)
        if constexpr (!IS_L0) {
            if (tid < H) {
                int tn = (t + 1 < tc) ? t + 1 : t;
                const float* gp = gxb + (size_t)tn * GATES;
                n0 = gp[tid]; n1 = gp[tid + 128];
                n2 = gp[tid + 256]; n3 = gp[tid + 384];
            }
        }
        float4 hA = sh4[4*ks], hB = sh4[4*ks+1], hC = sh4[4*ks+2], hD = sh4[4*ks+3];
        float a0 = dot4f(w03,hD, dot4f(w02,hC, dot4f(w01,hB, dot4f(w00,hA, 0.f))));
        float a1 = dot4f(w13,hD, dot4f(w12,hC, dot4f(w11,hB, dot4f(w10,hA, 0.f))));
        float a2 = dot4f(w23,hD, dot4f(w22,hC, dot4f(w21,hB, dot4f(w20,hA, 0.f))));
        float a3 = dot4f(w33,hD, dot4f(w32,hC, dot4f(w31,hB, dot4f(w30,hA, 0.f))));
        if constexpr (IS_L0) {
            if (ks >= 1 && ks <= 3) {
                float4 xq = *(const float4*)(sh_x + t * IN_ + 4 * (ks - 1));
                a0 = dot4f(wx0, xq, a0); a1 = dot4f(wx1, xq, a1);
                a2 = dot4f(wx2, xq, a2); a3 = dot4f(wx3, xq, a3);
            }
        }
        float4 av; av.x = a0; av.y = a1; av.z = a2; av.w = a3;
        sp4w[ks * 128 + q] = av;                 // one ds_write_b128
        __syncthreads();

        // ---- phase 2: reduce + activate + state update (tid<128) ----
        if (tid < H) {
            float pi = 0, pf = 0, pg = 0, po = 0;
#define RQ(m) { float4 v = sp4[m * 128 + tid]; pi += v.x; pf += v.y; pg += v.z; po += v.w; }
            RQ(0) RQ(1) RQ(2) RQ(3) RQ(4) RQ(5) RQ(6) RQ(7)
#undef RQ
            float gi, gf, gg, go;
            if constexpr (IS_L0) {
                gi = pi + bias0; gf = pf + bias1; gg = pg + bias2; go = po + bias3;
            } else {
                gi = pi + cur0; gf = pf + cur1; gg = pg + cur2; go = po + cur3;
                cur0 = n0; cur1 = n1; cur2 = n2; cur3 = n3;
            }
            creg = fmaf(sigmoidf_(gf), creg, sigmoidf_(gi) * tanhf_(gg));
            hreg = sigmoidf_(go) * tanhf_(creg);
            sh_h[tid] = hreg;
            if constexpr (IS_L0) hs_out[(size_t)t * H + tid] = hreg;
        }
        __syncthreads();
    }
    if (tid < H) { state[b*2*H + tid] = hreg; state[b*2*H + H + tid] = creg; }
}

// ======================= gx1 GEMM =======================
// gx1[b,t,g] = bias1[g] + sum_k hs0[b,t,k] * Wih1[g,k]
// 512 threads, thread = gate g; block = (b, 64-step tile).
// W row pinned in 32 NAMED float4 BEFORE the t-loop (round 4: compiler
// interchanged the loops and re-streamed W per t -> 30ms dispatch, VGPR=28).
// h-tile read through block-uniform pointers -> scalar s_load; each FMA is
// v_fma(v_w, s_h, acc): no LDS, no per-lane vector loads except gx store.
__global__ __launch_bounds__(512)
__attribute__((amdgpu_waves_per_eu(2, 2)))
void gx1_gemm(const float* __restrict__ hs0, const float* __restrict__ Wih,
              const float* __restrict__ bih, const float* __restrict__ bhh,
              float* __restrict__ gx, int tc)
{
    const int b  = blockIdx.x;
    const int t0 = blockIdx.y * TT;
    const int g  = threadIdx.x;

#define LWG(j) float4 w##j = ((const float4*)(Wih + (size_t)g * H))[j];
    REP32(LWG)
#undef LWG
    const float biasg = bih[g] + bhh[g];

    const float* hp = hs0 + ((size_t)b * tc + t0) * H;      // block-uniform
    float* gxo = gx + ((size_t)b * tc + t0) * GATES + g;

    for (int t = 0; t < TT; ++t) {
        const float4* h4 = (const float4*)(hp + (size_t)t * H);  // uniform -> s_load
        float a0 = biasg, a1 = 0.f, a2 = 0.f, a3 = 0.f;
#define G4(i0,i1,i2,i3) \
        a0 = dot4f(w##i0, h4[i0], a0); a1 = dot4f(w##i1, h4[i1], a1); \
        a2 = dot4f(w##i2, h4[i2], a2); a3 = dot4f(w##i3, h4[i3], a3);
        G4(0,1,2,3)    G4(4,5,6,7)    G4(8,9,10,11)   G4(12,13,14,15)
        G4(16,17,18,19) G4(20,21,22,23) G4(24,25,26,27) G4(28,29,30,31)
#undef G4
        gxo[(size_t)t * GATES] = (a0 + a1) + (a2 + a3);     // coalesced b32
    }
}

// ======================= output projection =======================
__global__ void out_proj(const float* __restrict__ state1,
                         const float* __restrict__ Wout,
                         const float* __restrict__ bout,
                         float* __restrict__ out)
{
    const int b = blockIdx.x, j = threadIdx.x;
    __shared__ float sh[H];
    if (j < H) sh[j] = state1[b*2*H + j];
    __syncthreads();
    if (j < 4) {
        float a = bout[j];
        for (int k = 0; k < H; ++k) a = fmaf(Wout[j*H + k], sh[k], a);
        out[b*4 + j] = a;
    }
}

extern "C" void kernel_launch(void* const* d_in, const int* in_sizes, int n_in,
                              void* d_out, int out_size, void* d_ws, size_t ws_size,
                              hipStream_t stream)
{
    const float* x    = (const float*)d_in[0];
    const float* Wih0 = (const float*)d_in[1];
    const float* Whh0 = (const float*)d_in[2];
    const float* bih0 = (const float*)d_in[3];
    const float* bhh0 = (const float*)d_in[4];
    const float* Wih1 = (const float*)d_in[5];
    const float* Whh1 = (const float*)d_in[6];
    const float* bih1 = (const float*)d_in[7];
    const float* bhh1 = (const float*)d_in[8];
    const float* Wout = (const float*)d_in[9];
    const float* bout = (const float*)d_in[10];

    // ws layout: st0 | st1 | hs0 chunk | gx1 chunk  (tc >= TT for gemm grid)
    int tc = TT;
    for (int cand = TCMAX; cand >= TT; cand >>= 1) {
        size_t need = (size_t)2 * B_ * 2 * H * 4
                    + (size_t)B_ * cand * H * 4
                    + (size_t)B_ * cand * GATES * 4;
        if (need <= ws_size) { tc = cand; break; }
    }

    float* ws  = (float*)d_ws;
    float* st0 = ws;
    float* st1 = st0 + (size_t)B_ * 2 * H;
    float* hs0 = st1 + (size_t)B_ * 2 * H;
    float* gx1 = hs0 + (size_t)B_ * tc * H;

    const size_t shm_l0 = (size_t)(8 * 512 + H + tc * IN_) * 4;
    const size_t shm_l1 = (size_t)(8 * 512 + H) * 4;

    const int nchunks = T_ / tc;
    for (int c = 0; c < nchunks; ++c) {
        lstm_scan<true><<<B_, 1024, shm_l0, stream>>>(
            x, Wih0, Whh0, bih0, bhh0, hs0, st0, tc, c);
        gx1_gemm<<<dim3(B_, tc / TT), 512, 0, stream>>>(
            hs0, Wih1, bih1, bhh1, gx1, tc);
        lstm_scan<false><<<B_, 1024, shm_l1, stream>>>(
            gx1, nullptr, Whh1, nullptr, nullptr, nullptr, st1, tc, c);
    }
    out_proj<<<B_, 128, 0, stream>>>(st1, Wout, bout, (float*)d_out);
}

// Round 8
// 7903.083 us; speedup vs baseline: 1.0021x; 1.0009x over previous
//
#include <hip/hip_runtime.h>
#include <cstdint>
#include <cstddef>

#define H      128
#define IN_    12
#define GATES  512   // 4*H
#define B_     256
#define T_     2048
#define TCMAX  512
#define TT     64    // gemm time-tile

#define REP32(M) M(0) M(1) M(2) M(3) M(4) M(5) M(6) M(7) M(8) M(9) M(10) M(11) \
  M(12) M(13) M(14) M(15) M(16) M(17) M(18) M(19) M(20) M(21) M(22) M(23) \
  M(24) M(25) M(26) M(27) M(28) M(29) M(30) M(31)

__device__ __forceinline__ float sigmoidf_(float x) {
    return 1.f / (1.f + __expf(-x));
}
__device__ __forceinline__ float tanhf_(float x) {
    return 2.f / (1.f + __expf(-2.f * x)) - 1.f;
}
__device__ __forceinline__ float dot4f(float4 w, float4 h, float a) {
    return fmaf(w.x, h.x, fmaf(w.y, h.y, fmaf(w.z, h.z, fmaf(w.w, h.w, a))));
}

// ======================= LSTM scan (both layers) =======================
// 1024 threads = 16 waves. thread -> (ks = tid>>7 wave-uniform k-window,
// q = tid&127 hidden index). Thread owns the 4 GATE rows of hidden q
// (rows q, 128+q, 256+q, 384+q), k-window [16ks,16ks+16) -> 16 float4 = 64 VGPR.
// Gate-major row ownership => phase-1 partial = one ds_write_b128 at
// [ks][q], phase-2 = 8 conflict-free ds_read_b128 at [ks][tid]
// (round-4 layout had 32 b32 reads at 4-way conflict: 2.5e7/dispatch).
template<bool IS_L0>
__global__ __launch_bounds__(1024) void lstm_scan(
    const float* __restrict__ x_or_gx,   // L0: x [B,T,12]; L1: gx chunk [B,tc,512]
    const float* __restrict__ Wih,       // L0 only [512,12]
    const float* __restrict__ Whh,       // [512,128]
    const float* __restrict__ bih, const float* __restrict__ bhh, // L0 only
    float* __restrict__ hs0,             // L0: out [B,tc,128]; L1: unused
    float* __restrict__ state,           // [B,2,128]
    int tc, int chunk)
{
    const int b   = blockIdx.x;
    const int tid = threadIdx.x;
    const int ks  = tid >> 7;    // 0..7, wave-uniform
    const int q   = tid & 127;   // hidden index

    extern __shared__ float smem[];
    float* sh_part = smem;                  // [8][128] float4 = 16 KB
    float* sh_h    = smem + 8 * 512;        // 128
    float* sh_x    = sh_h + H;              // L0: tc*12

    // resident W_hh fragment: gate rows i*128+q, cols 16ks..16ks+15
#define LOADW(i) \
    const float4* wr##i = (const float4*)(Whh + (size_t)(i * H + q) * H + 16 * ks); \
    float4 w##i##0 = wr##i[0], w##i##1 = wr##i[1], w##i##2 = wr##i[2], w##i##3 = wr##i[3];
    LOADW(0) LOADW(1) LOADW(2) LOADW(3)
#undef LOADW

    // L0: x-proj weights for ks 1..3 (4 floats per gate row)
    float4 wx0 = {0,0,0,0}, wx1 = {0,0,0,0}, wx2 = {0,0,0,0}, wx3 = {0,0,0,0};
    if constexpr (IS_L0) {
        if (ks >= 1 && ks <= 3) {
            wx0 = *(const float4*)(Wih + (size_t)(0 * H + q) * IN_ + 4 * (ks - 1));
            wx1 = *(const float4*)(Wih + (size_t)(1 * H + q) * IN_ + 4 * (ks - 1));
            wx2 = *(const float4*)(Wih + (size_t)(2 * H + q) * IN_ + 4 * (ks - 1));
            wx3 = *(const float4*)(Wih + (size_t)(3 * H + q) * IN_ + 4 * (ks - 1));
        }
        const float* xs = x_or_gx + ((size_t)b * T_ + (size_t)chunk * tc) * IN_;
        for (int i = tid; i < tc * IN_; i += 1024) sh_x[i] = xs[i];
    }

    // epilogue-thread state (tid<128)
    float bias0 = 0, bias1 = 0, bias2 = 0, bias3 = 0;
    float cur0 = 0, cur1 = 0, cur2 = 0, cur3 = 0;
    float hreg = 0.f, creg = 0.f;
    const float* gxb = nullptr;
    if constexpr (!IS_L0) gxb = x_or_gx + (size_t)b * tc * GATES;

    if (tid < H) {
        if constexpr (IS_L0) {
            bias0 = bih[tid]       + bhh[tid];
            bias1 = bih[tid + 128] + bhh[tid + 128];
            bias2 = bih[tid + 256] + bhh[tid + 256];
            bias3 = bih[tid + 384] + bhh[tid + 384];
        } else {
            cur0 = gxb[tid]; cur1 = gxb[tid + 128];
            cur2 = gxb[tid + 256]; cur3 = gxb[tid + 384];
        }
        if (chunk) { hreg = state[b*2*H + tid]; creg = state[b*2*H + H + tid]; }
        sh_h[tid] = hreg;
    }
    __syncthreads();

    float* hs_out = nullptr;
    if constexpr (IS_L0) hs_out = hs0 + (size_t)b * tc * H;

    const float4* sh4 = (const float4*)sh_h;
    float4* sp4w = (float4*)sh_part;
    const float4* sp4 = (const float4*)sh_part;

    for (int t = 0; t < tc; ++t) {
        // ---- phase 1: partial dots (all 16 waves) ----
        float n0 = 0, n1 = 0, n2 = 0, n3 = 0;   // next-step gx prefetch (L1)
        if constexpr (!IS_L0) {
            if (tid < H) {
                int tn = (t + 1 < tc) ? t + 1 : t;
                const float* gp = gxb + (size_t)tn * GATES;
                n0 = gp[tid]; n1 = gp[tid + 128];
                n2 = gp[tid + 256]; n3 = gp[tid + 384];
            }
        }
        float4 hA = sh4[4*ks], hB = sh4[4*ks+1], hC = sh4[4*ks+2], hD = sh4[4*ks+3];
        float a0 = dot4f(w03,hD, dot4f(w02,hC, dot4f(w01,hB, dot4f(w00,hA, 0.f))));
        float a1 = dot4f(w13,hD, dot4f(w12,hC, dot4f(w11,hB, dot4f(w10,hA, 0.f))));
        float a2 = dot4f(w23,hD, dot4f(w22,hC, dot4f(w21,hB, dot4f(w20,hA, 0.f))));
        float a3 = dot4f(w33,hD, dot4f(w32,hC, dot4f(w31,hB, dot4f(w30,hA, 0.f))));
        if constexpr (IS_L0) {
            if (ks >= 1 && ks <= 3) {
                float4 xq = *(const float4*)(sh_x + t * IN_ + 4 * (ks - 1));
                a0 = dot4f(wx0, xq, a0); a1 = dot4f(wx1, xq, a1);
                a2 = dot4f(wx2, xq, a2); a3 = dot4f(wx3, xq, a3);
            }
        }
        float4 av; av.x = a0; av.y = a1; av.z = a2; av.w = a3;
        sp4w[ks * 128 + q] = av;                 // one ds_write_b128
        __syncthreads();

        // ---- phase 2: reduce + activate + state update (tid<128) ----
        if (tid < H) {
            float pi = 0, pf = 0, pg = 0, po = 0;
#define RQ(m) { float4 v = sp4[m * 128 + tid]; pi += v.x; pf += v.y; pg += v.z; po += v.w; }
            RQ(0) RQ(1) RQ(2) RQ(3) RQ(4) RQ(5) RQ(6) RQ(7)
#undef RQ
            float gi, gf, gg, go;
            if constexpr (IS_L0) {
                gi = pi + bias0; gf = pf + bias1; gg = pg + bias2; go = po + bias3;
            } else {
                gi = pi + cur0; gf = pf + cur1; gg = pg + cur2; go = po + cur3;
                cur0 = n0; cur1 = n1; cur2 = n2; cur3 = n3;
            }
            creg = fmaf(sigmoidf_(gf), creg, sigmoidf_(gi) * tanhf_(gg));
            hreg = sigmoidf_(go) * tanhf_(creg);
            sh_h[tid] = hreg;
            if constexpr (IS_L0) hs_out[(size_t)t * H + tid] = hreg;
        }
        __syncthreads();
    }
    if (tid < H) { state[b*2*H + tid] = hreg; state[b*2*H + H + tid] = creg; }
}

// ======================= gx1 GEMM =======================
// gx1[b,t,g] = bias1[g] + sum_k hs0[b,t,k] * Wih1[g,k]
// 512 threads, thread = gate g; block = (b, 64-step tile).
// W row pinned in 32 NAMED float4 BEFORE the t-loop (round 4: compiler
// interchanged the loops and re-streamed W per t -> 30ms dispatch, VGPR=28).
// h-tile read through block-uniform pointers -> scalar s_load; each FMA is
// v_fma(v_w, s_h, acc): no LDS, no per-lane vector loads except gx store.
__global__ __launch_bounds__(512)
__attribute__((amdgpu_waves_per_eu(2, 2)))
void gx1_gemm(const float* __restrict__ hs0, const float* __restrict__ Wih,
              const float* __restrict__ bih, const float* __restrict__ bhh,
              float* __restrict__ gx, int tc)
{
    const int b  = blockIdx.x;
    const int t0 = blockIdx.y * TT;
    const int g  = threadIdx.x;

#define LWG(j) float4 w##j = ((const float4*)(Wih + (size_t)g * H))[j];
    REP32(LWG)
#undef LWG
    const float biasg = bih[g] + bhh[g];

    const float* hp = hs0 + ((size_t)b * tc + t0) * H;      // block-uniform
    float* gxo = gx + ((size_t)b * tc + t0) * GATES + g;

    for (int t = 0; t < TT; ++t) {
        const float4* h4 = (const float4*)(hp + (size_t)t * H);  // uniform -> s_load
        float a0 = biasg, a1 = 0.f, a2 = 0.f, a3 = 0.f;
#define G4(i0,i1,i2,i3) \
        a0 = dot4f(w##i0, h4[i0], a0); a1 = dot4f(w##i1, h4[i1], a1); \
        a2 = dot4f(w##i2, h4[i2], a2); a3 = dot4f(w##i3, h4[i3], a3);
        G4(0,1,2,3)    G4(4,5,6,7)    G4(8,9,10,11)   G4(12,13,14,15)
        G4(16,17,18,19) G4(20,21,22,23) G4(24,25,26,27) G4(28,29,30,31)
#undef G4
        gxo[(size_t)t * GATES] = (a0 + a1) + (a2 + a3);     // coalesced b32
    }
}

// ======================= output projection =======================
__global__ void out_proj(const float* __restrict__ state1,
                         const float* __restrict__ Wout,
                         const float* __restrict__ bout,
                         float* __restrict__ out)
{
    const int b = blockIdx.x, j = threadIdx.x;
    __shared__ float sh[H];
    if (j < H) sh[j] = state1[b*2*H + j];
    __syncthreads();
    if (j < 4) {
        float a = bout[j];
        for (int k = 0; k < H; ++k) a = fmaf(Wout[j*H + k], sh[k], a);
        out[b*4 + j] = a;
    }
}

extern "C" void kernel_launch(void* const* d_in, const int* in_sizes, int n_in,
                              void* d_out, int out_size, void* d_ws, size_t ws_size,
                              hipStream_t stream)
{
    const float* x    = (const float*)d_in[0];
    const float* Wih0 = (const float*)d_in[1];
    const float* Whh0 = (const float*)d_in[2];
    const float* bih0 = (const float*)d_in[3];
    const float* bhh0 = (const float*)d_in[4];
    const float* Wih1 = (const float*)d_in[5];
    const float* Whh1 = (const float*)d_in[6];
    const float* bih1 = (const float*)d_in[7];
    const float* bhh1 = (const float*)d_in[8];
    const float* Wout = (const float*)d_in[9];
    const float* bout = (const float*)d_in[10];

    // ws layout: st0 | st1 | hs0 chunk | gx1 chunk  (tc >= TT for gemm grid)
    int tc = TT;
    for (int cand = TCMAX; cand >= TT; cand >>= 1) {
        size_t need = (size_t)2 * B_ * 2 * H * 4
                    + (size_t)B_ * cand * H * 4
                    + (size_t)B_ * cand * GATES * 4;
        if (need <= ws_size) { tc = cand; break; }
    }

    float* ws  = (float*)d_ws;
    float* st0 = ws;
    float* st1 = st0 + (size_t)B_ * 2 * H;
    float* hs0 = st1 + (size_t)B_ * 2 * H;
    float* gx1 = hs0 + (size_t)B_ * tc * H;

    const size_t shm_l0 = (size_t)(8 * 512 + H + tc * IN_) * 4;
    const size_t shm_l1 = (size_t)(8 * 512 + H) * 4;

    const int nchunks = T_ / tc;
    for (int c = 0; c < nchunks; ++c) {
        lstm_scan<true><<<B_, 1024, shm_l0, stream>>>(
            x, Wih0, Whh0, bih0, bhh0, hs0, st0, tc, c);
        gx1_gemm<<<dim3(B_, tc / TT), 512, 0, stream>>>(
            hs0, Wih1, bih1, bhh1, gx1, tc);
        lstm_scan<false><<<B_, 1024, shm_l1, stream>>>(
            gx1, nullptr, Whh1, nullptr, nullptr, nullptr, st1, tc, c);
    }
    out_proj<<<B_, 128, 0, stream>>>(st1, Wout, bout, (float*)d_out);
}

// Round 9
// 5653.272 us; speedup vs baseline: 1.4009x; 1.3980x over previous
//
#include <hip/hip_runtime.h>
#include <cstdint>
#include <cstddef>

#define H      128
#define IN_    12
#define GATES  512   // 4*H
#define B_     256
#define T_     2048
#define TCMAX  512
#define TT     64    // gemm time-tile
#define PS     520   // sh_part ks-stride (512 rows + pad)

#define REP32(M) M(0) M(1) M(2) M(3) M(4) M(5) M(6) M(7) M(8) M(9) M(10) M(11) \
  M(12) M(13) M(14) M(15) M(16) M(17) M(18) M(19) M(20) M(21) M(22) M(23) \
  M(24) M(25) M(26) M(27) M(28) M(29) M(30) M(31)

__device__ __forceinline__ float sigmoidf_(float x) {
    return 1.f / (1.f + __expf(-x));
}
__device__ __forceinline__ float tanhf_(float x) {
    return 2.f / (1.f + __expf(-2.f * x)) - 1.f;
}
__device__ __forceinline__ float dot4f(float4 w, float4 h, float a) {
    return fmaf(w.x, h.x, fmaf(w.y, h.y, fmaf(w.z, h.z, fmaf(w.w, h.w, a))));
}

// ======================= LSTM scan (both layers) =======================
// EXACT round-4 version (measured 271 us/chunk, VGPR=56). Round-8's
// "conflict-fix" layout regressed scans ~2x; reverted wholesale.
template<bool IS_L0>
__global__ __launch_bounds__(1024) void lstm_scan(
    const float* __restrict__ x_or_gx,   // L0: x [B,T,12]; L1: gx chunk [B,tc,512]
    const float* __restrict__ Wih,       // L0 only [512,12]
    const float* __restrict__ Whh,       // [512,128]
    const float* __restrict__ bih, const float* __restrict__ bhh, // L0 only
    float* __restrict__ hs0,             // L0: out [B,tc,128]; L1: unused
    float* __restrict__ state,           // [B,2,128]
    int tc, int chunk)
{
    const int b   = blockIdx.x;
    const int tid = threadIdx.x;
    const int ks  = tid >> 7;    // 0..7
    const int q   = tid & 127;   // row quad

    extern __shared__ float smem[];
    float* sh_part = smem;                  // 8*PS
    float* sh_h    = smem + 8 * PS;         // 128
    float* sh_x    = sh_h + H;              // L0: tc*12

    // resident W_hh fragment: rows 4q..4q+3, cols 16ks..16ks+15
#define LOADW(i) \
    const float4* wr##i = (const float4*)(Whh + (size_t)(4*q+i)*H + 16*ks); \
    float4 w##i##0 = wr##i[0], w##i##1 = wr##i[1], w##i##2 = wr##i[2], w##i##3 = wr##i[3];
    LOADW(0) LOADW(1) LOADW(2) LOADW(3)
#undef LOADW

    // L0: x-proj weights for ks 1..3 (4 floats per row)
    float4 wx0 = {0,0,0,0}, wx1 = {0,0,0,0}, wx2 = {0,0,0,0}, wx3 = {0,0,0,0};
    if constexpr (IS_L0) {
        if (ks >= 1 && ks <= 3) {
            wx0 = *(const float4*)(Wih + (size_t)(4*q+0)*IN_ + 4*(ks-1));
            wx1 = *(const float4*)(Wih + (size_t)(4*q+1)*IN_ + 4*(ks-1));
            wx2 = *(const float4*)(Wih + (size_t)(4*q+2)*IN_ + 4*(ks-1));
            wx3 = *(const float4*)(Wih + (size_t)(4*q+3)*IN_ + 4*(ks-1));
        }
        const float* xs = x_or_gx + ((size_t)b * T_ + (size_t)chunk * tc) * IN_;
        for (int i = tid; i < tc * IN_; i += 1024) sh_x[i] = xs[i];
    }

    // epilogue-thread state (tid<128)
    float bias0 = 0, bias1 = 0, bias2 = 0, bias3 = 0;
    float cur0 = 0, cur1 = 0, cur2 = 0, cur3 = 0;
    float hreg = 0.f, creg = 0.f;
    const float* gxb = nullptr;
    if constexpr (!IS_L0) gxb = x_or_gx + (size_t)b * tc * GATES;

    if (tid < H) {
        if constexpr (IS_L0) {
            bias0 = bih[tid]       + bhh[tid];
            bias1 = bih[tid + 128] + bhh[tid + 128];
            bias2 = bih[tid + 256] + bhh[tid + 256];
            bias3 = bih[tid + 384] + bhh[tid + 384];
        } else {
            cur0 = gxb[tid]; cur1 = gxb[tid + 128];
            cur2 = gxb[tid + 256]; cur3 = gxb[tid + 384];
        }
        if (chunk) { hreg = state[b*2*H + tid]; creg = state[b*2*H + H + tid]; }
        sh_h[tid] = hreg;
    }
    __syncthreads();

    float* hs_out = nullptr;
    if constexpr (IS_L0) hs_out = hs0 + (size_t)b * tc * H;

    const float4* sh4 = (const float4*)sh_h;
    const int i0 = tid & 3, q0 = tid >> 2;   // phase-2 partial coords

    for (int t = 0; t < tc; ++t) {
        // ---- phase 1: partial dots (all 16 waves) ----
        float n0 = 0, n1 = 0, n2 = 0, n3 = 0;   // next-step gx prefetch
        if constexpr (!IS_L0) {
            if (tid < H) {
                int tn = (t + 1 < tc) ? t + 1 : t;
                const float* gp = gxb + (size_t)tn * GATES;
                n0 = gp[tid]; n1 = gp[tid + 128];
                n2 = gp[tid + 256]; n3 = gp[tid + 384];
            }
        }
        float4 hA = sh4[4*ks], hB = sh4[4*ks+1], hC = sh4[4*ks+2], hD = sh4[4*ks+3];
        float a0 = dot4f(w03,hD, dot4f(w02,hC, dot4f(w01,hB, dot4f(w00,hA, 0.f))));
        float a1 = dot4f(w13,hD, dot4f(w12,hC, dot4f(w11,hB, dot4f(w10,hA, 0.f))));
        float a2 = dot4f(w23,hD, dot4f(w22,hC, dot4f(w21,hB, dot4f(w20,hA, 0.f))));
        float a3 = dot4f(w33,hD, dot4f(w32,hC, dot4f(w31,hB, dot4f(w30,hA, 0.f))));
        if constexpr (IS_L0) {
            if (ks >= 1 && ks <= 3) {
                float4 xq = *(const float4*)(sh_x + t * IN_ + 4*(ks-1));
                a0 = dot4f(wx0, xq, a0); a1 = dot4f(wx1, xq, a1);
                a2 = dot4f(wx2, xq, a2); a3 = dot4f(wx3, xq, a3);
            }
        }
        sh_part[ks*PS + 0*128 + q] = a0;
        sh_part[ks*PS + 1*128 + q] = a1;
        sh_part[ks*PS + 2*128 + q] = a2;
        sh_part[ks*PS + 3*128 + q] = a3;
        __syncthreads();

        // ---- phase 2: reduce + activate + state update (tid<128) ----
        if (tid < H) {
            float p0, p1, p2, p3;
            {
                const float* pb = sh_part + i0*128 + q0;
#define RSUM(m, dst) { \
                float s = pb[32*m]; \
                s += pb[32*m + 1*PS]; s += pb[32*m + 2*PS]; s += pb[32*m + 3*PS]; \
                s += pb[32*m + 4*PS]; s += pb[32*m + 5*PS]; s += pb[32*m + 6*PS]; \
                s += pb[32*m + 7*PS]; dst = s; }
                RSUM(0, p0) RSUM(1, p1) RSUM(2, p2) RSUM(3, p3)
#undef RSUM
            }
            float gi, gf, gg, go;
            if constexpr (IS_L0) {
                gi = p0 + bias0; gf = p1 + bias1; gg = p2 + bias2; go = p3 + bias3;
            } else {
                gi = p0 + cur0; gf = p1 + cur1; gg = p2 + cur2; go = p3 + cur3;
                cur0 = n0; cur1 = n1; cur2 = n2; cur3 = n3;
            }
            creg = fmaf(sigmoidf_(gf), creg, sigmoidf_(gi) * tanhf_(gg));
            hreg = sigmoidf_(go) * tanhf_(creg);
            sh_h[tid] = hreg;
            if constexpr (IS_L0) hs_out[(size_t)t * H + tid] = hreg;
        }
        __syncthreads();
    }
    if (tid < H) { state[b*2*H + tid] = hreg; state[b*2*H + H + tid] = creg; }
}

// ======================= gx1 GEMM =======================
// gx1[b,t,g] = bias1[g] + sum_k hs0[b,t,k] * Wih1[g,k]
// thread = gate g, W row in 32 named float4 (proven resident, VGPR=128).
// h row is wave-uniform -> delivered via s_load_dwordx16 into SGPRs
// (round 8: vector-path h reloads left VALUBusy=47%, 5.4x off floor).
// s_waitcnt lives INSIDE the asm that defines the values, so register
// dataflow orders all consumers after the wait (rule-18 safe).
typedef __attribute__((ext_vector_type(16))) float f16x;

__global__ __launch_bounds__(512)
void gx1_gemm(const float* __restrict__ hs0, const float* __restrict__ Wih,
              const float* __restrict__ bih, const float* __restrict__ bhh,
              float* __restrict__ gx, int tc)
{
    const int b  = blockIdx.x;
    const int t0 = blockIdx.y * TT;
    const int g  = threadIdx.x;

#define LWG(j) float4 w##j = ((const float4*)(Wih + (size_t)g * H))[j];
    REP32(LWG)
#undef LWG
    const float biasg = bih[g] + bhh[g];

    const float* hp = hs0 + ((size_t)b * tc + t0) * H;      // block-uniform
    float* gxo = gx + ((size_t)b * tc + t0) * GATES + g;

    for (int t = 0; t < TT; ++t) {
        const float* hpt = hp + (size_t)t * H;
        float a0 = biasg, a1 = 0.f, a2 = 0.f, a3 = 0.f;

        f16x h0, h1, h2, h3;
        // ---- first half of h row: 64 floats into 64 SGPRs ----
        asm volatile(
            "s_load_dwordx16 %0, %4, 0x0\n\t"
            "s_load_dwordx16 %1, %4, 0x40\n\t"
            "s_load_dwordx16 %2, %4, 0x80\n\t"
            "s_load_dwordx16 %3, %4, 0xc0\n\t"
            "s_waitcnt lgkmcnt(0)"
            : "=s"(h0), "=s"(h1), "=s"(h2), "=s"(h3)
            : "s"(hpt));
#define FMA16(hv, base) { \
        a0 = fmaf(w##base.x, hv.s0, a0);  a1 = fmaf(w##base.y, hv.s1, a1); \
        a2 = fmaf(w##base.z, hv.s2, a2);  a3 = fmaf(w##base.w, hv.s3, a3); }
#define Q4(hv, j0, j1, j2, j3) { \
        a0 = fmaf(w##j0.x, hv.s0, a0); a1 = fmaf(w##j0.y, hv.s1, a1); \
        a2 = fmaf(w##j0.z, hv.s2, a2); a3 = fmaf(w##j0.w, hv.s3, a3); \
        a0 = fmaf(w##j1.x, hv.s4, a0); a1 = fmaf(w##j1.y, hv.s5, a1); \
        a2 = fmaf(w##j1.z, hv.s6, a2); a3 = fmaf(w##j1.w, hv.s7, a3); \
        a0 = fmaf(w##j2.x, hv.s8, a0); a1 = fmaf(w##j2.y, hv.s9, a1); \
        a2 = fmaf(w##j2.z, hv.sa, a2); a3 = fmaf(w##j2.w, hv.sb, a3); \
        a0 = fmaf(w##j3.x, hv.sc, a0); a1 = fmaf(w##j3.y, hv.sd, a1); \
        a2 = fmaf(w##j3.z, hv.se, a2); a3 = fmaf(w##j3.w, hv.sf, a3); }
        Q4(h0, 0, 1, 2, 3)    Q4(h1, 4, 5, 6, 7)
        Q4(h2, 8, 9, 10, 11)  Q4(h3, 12, 13, 14, 15)

        // ---- second half ----
        asm volatile(
            "s_load_dwordx16 %0, %4, 0x100\n\t"
            "s_load_dwordx16 %1, %4, 0x140\n\t"
            "s_load_dwordx16 %2, %4, 0x180\n\t"
            "s_load_dwordx16 %3, %4, 0x1c0\n\t"
            "s_waitcnt lgkmcnt(0)"
            : "=s"(h0), "=s"(h1), "=s"(h2), "=s"(h3)
            : "s"(hpt));
        Q4(h0, 16, 17, 18, 19)  Q4(h1, 20, 21, 22, 23)
        Q4(h2, 24, 25, 26, 27)  Q4(h3, 28, 29, 30, 31)
#undef Q4
#undef FMA16

        gxo[(size_t)t * GATES] = (a0 + a1) + (a2 + a3);     // coalesced b32
    }
}

// ======================= output projection =======================
__global__ void out_proj(const float* __restrict__ state1,
                         const float* __restrict__ Wout,
                         const float* __restrict__ bout,
                         float* __restrict__ out)
{
    const int b = blockIdx.x, j = threadIdx.x;
    __shared__ float sh[H];
    if (j < H) sh[j] = state1[b*2*H + j];
    __syncthreads();
    if (j < 4) {
        float a = bout[j];
        for (int k = 0; k < H; ++k) a = fmaf(Wout[j*H + k], sh[k], a);
        out[b*4 + j] = a;
    }
}

extern "C" void kernel_launch(void* const* d_in, const int* in_sizes, int n_in,
                              void* d_out, int out_size, void* d_ws, size_t ws_size,
                              hipStream_t stream)
{
    const float* x    = (const float*)d_in[0];
    const float* Wih0 = (const float*)d_in[1];
    const float* Whh0 = (const float*)d_in[2];
    const float* bih0 = (const float*)d_in[3];
    const float* bhh0 = (const float*)d_in[4];
    const float* Wih1 = (const float*)d_in[5];
    const float* Whh1 = (const float*)d_in[6];
    const float* bih1 = (const float*)d_in[7];
    const float* bhh1 = (const float*)d_in[8];
    const float* Wout = (const float*)d_in[9];
    const float* bout = (const float*)d_in[10];

    // ws layout: st0 | st1 | hs0 chunk | gx1 chunk  (tc >= TT for gemm grid)
    int tc = TT;
    for (int cand = TCMAX; cand >= TT; cand >>= 1) {
        size_t need = (size_t)2 * B_ * 2 * H * 4
                    + (size_t)B_ * cand * H * 4
                    + (size_t)B_ * cand * GATES * 4;
        if (need <= ws_size) { tc = cand; break; }
    }

    float* ws  = (float*)d_ws;
    float* st0 = ws;
    float* st1 = st0 + (size_t)B_ * 2 * H;
    float* hs0 = st1 + (size_t)B_ * 2 * H;
    float* gx1 = hs0 + (size_t)B_ * tc * H;

    const size_t shm_l0 = (size_t)(8 * PS + H + tc * IN_) * 4;
    const size_t shm_l1 = (size_t)(8 * PS + H) * 4;

    const int nchunks = T_ / tc;
    for (int c = 0; c < nchunks; ++c) {
        lstm_scan<true><<<B_, 1024, shm_l0, stream>>>(
            x, Wih0, Whh0, bih0, bhh0, hs0, st0, tc, c);
        gx1_gemm<<<dim3(B_, tc / TT), 512, 0, stream>>>(
            hs0, Wih1, bih1, bhh1, gx1, tc);
        lstm_scan<false><<<B_, 1024, shm_l1, stream>>>(
            gx1, nullptr, Whh1, nullptr, nullptr, nullptr, st1, tc, c);
    }
    out_proj<<<B_, 128, 0, stream>>>(st1, Wout, bout, (float*)d_out);
}